// Round 9
// baseline (175.614 us; speedup 1.0000x reference)
//
#include <hip/hip_runtime.h>
#include <stdint.h>
#include <stddef.h>

typedef _Float16 f16;
typedef f16 f16x4 __attribute__((ext_vector_type(4)));
typedef f16 f16x8 __attribute__((ext_vector_type(8)));
typedef float f32x4 __attribute__((ext_vector_type(4)));

#define DEV __device__ __forceinline__

constexpr int Bb = 4, Nn = 8192, Mm = 2048, C1 = 128, C2 = 256;
constexpr int K0 = 384, CO = 256;

// ---------------------------------------------------------------- 1a) three_nn scan: query-per-thread, broadcast LDS
// Block = 256 queries x 512 known pts (4-way M split -> 512 blocks, 2/CU). All 64 lanes of a
// wave read the SAME kpts entry each iteration -> LDS broadcast (64x less LDS traffic than the
// slice layout; R8's version was LDS-BW-bound at ~20us of ds_read_b128). Per-pair math is the
// bit-exact np formulation: dot2 = (ux2*kx + uy2*ky) + uz2*kz == 2*einsum bitwise,
// dd = (uu - dot2) + kk.
__global__ __launch_bounds__(256) void knn_scan(
    const float* __restrict__ unknown, const float* __restrict__ known,
    float4* __restrict__ dscr, int4* __restrict__ iscr)
{
  __shared__ float  flat[1536];      // 6 KB raw coords
  __shared__ float4 kp4[512];        // 8 KB x,y,z,|k|^2
  const int t  = threadIdx.x;
  const int bx = blockIdx.x;         // = ((b*32 + qc)*4) + mp
  const int mp = bx & 3;
  const int qc = (bx >> 2) & 31;
  const int b  = bx >> 7;
  const int q  = qc * 256 + t;
  const int m0 = mp * 512;

  const float* kbase = known + (size_t)(b * Mm + m0) * 3;
#pragma unroll
  for (int j = 0; j < 6; ++j) flat[t + j * 256] = kbase[t + j * 256];
  __syncthreads();
#pragma unroll
  for (int j = 0; j < 2; ++j) {
    int p = t + j * 256;
    float kx = flat[3 * p], ky = flat[3 * p + 1], kz = flat[3 * p + 2];
    float kk = __fadd_rn(__fadd_rn(__fmul_rn(kx, kx), __fmul_rn(ky, ky)), __fmul_rn(kz, kz));
    kp4[p] = make_float4(kx, ky, kz, kk);
  }
  __syncthreads();

  float ux = unknown[(b * Nn + q) * 3 + 0];
  float uy = unknown[(b * Nn + q) * 3 + 1];
  float uz = unknown[(b * Nn + q) * 3 + 2];
  float uu = __fadd_rn(__fadd_rn(__fmul_rn(ux, ux), __fmul_rn(uy, uy)), __fmul_rn(uz, uz));
  float ux2 = ux + ux, uy2 = uy + uy, uz2 = uz + uz;   // exact exponent bump

  float d1 = 1e30f, d2 = 1e30f, d3 = 1e30f;
  int   i1 = 0, i2 = 0, i3 = 0;
#pragma unroll 8
  for (int it = 0; it < 512; ++it) {
    float4 kp = kp4[it];             // uniform address -> broadcast, conflict-free
    float dot2 = __fadd_rn(__fadd_rn(__fmul_rn(ux2, kp.x), __fmul_rn(uy2, kp.y)), __fmul_rn(uz2, kp.z));
    float dd   = __fadd_rn(__fsub_rn(uu, dot2), kp.w);
    int gm = m0 + it;
    bool c1 = dd < d1, c2 = dd < d2, c3 = dd < d3;
    i3 = c3 ? (c2 ? i2 : gm) : i3;
    i2 = c2 ? (c1 ? i1 : gm) : i2;
    i1 = c1 ? gm : i1;
    d3 = __builtin_amdgcn_fmed3f(dd, d2, d3);
    d2 = __builtin_amdgcn_fmed3f(dd, d1, d2);
    d1 = fminf(dd, d1);
  }

  dscr[(size_t)(b * Nn + q) * 4 + mp] = make_float4(d1, d2, d3, 0.f);
  iscr[(size_t)(b * Nn + q) * 4 + mp] = make_int4(i1, i2, i3, 0);
}

// ---------------------------------------------------------------- 1b) merge the 4 disjoint partial top-3s (exact, np-stable)
__global__ __launch_bounds__(256) void knn_merge(
    const float4* __restrict__ dscr, const int4* __restrict__ iscr,
    int* __restrict__ oidx, float* __restrict__ ow)
{
  const int gq = blockIdx.x * 256 + threadIdx.x;   // 0..B*Nn-1
  float d1 = 1e30f, d2 = 1e30f, d3 = 1e30f;
  int   i1 = 0, i2 = 0, i3 = 0;
#pragma unroll
  for (int p = 0; p < 4; ++p) {
    float4 dv = dscr[(size_t)gq * 4 + p];
    int4   iv = iscr[(size_t)gq * 4 + p];
    float ds[3] = {dv.x, dv.y, dv.z};
    int   is[3] = {iv.x, iv.y, iv.z};
#pragma unroll
    for (int u = 0; u < 3; ++u) {
      float e = ds[u]; int j = is[u];
      bool c3 = (e < d3) || (e == d3 && j < i3);
      bool c2 = (e < d2) || (e == d2 && j < i2);
      bool c1 = (e < d1) || (e == d1 && j < i1);
      d3 = c3 ? (c2 ? d2 : e) : d3;  i3 = c3 ? (c2 ? i2 : j) : i3;
      d2 = c2 ? (c1 ? d1 : e) : d2;  i2 = c2 ? (c1 ? i1 : j) : i2;
      d1 = c1 ? e : d1;              i1 = c1 ? j : i1;
    }
  }
  float t1 = sqrtf(fmaxf(d1, 0.f)), t2 = sqrtf(fmaxf(d2, 0.f)), t3 = sqrtf(fmaxf(d3, 0.f));
  float r1 = 1.f / (t1 + 1e-8f), r2 = 1.f / (t2 + 1e-8f), r3 = 1.f / (t3 + 1e-8f);
  float rs = __fadd_rn(__fadd_rn(r1, r2), r3);
  int base = gq * 3;
  oidx[base + 0] = i1; oidx[base + 1] = i2; oidx[base + 2] = i3;
  ow[base + 0] = r1 / rs; ow[base + 1] = r2 / rs; ow[base + 2] = r3 / rs;
}

// ---------------------------------------------------------------- 2) known_feats (B,C2,M) f32 -> kfT (B,M,C2) f16
__global__ __launch_bounds__(256) void kft_kernel(const float* __restrict__ kf, f16* __restrict__ kfT)
{
  __shared__ f16 tile[64][72];
  const int t = threadIdx.x;
  const int m0 = blockIdx.x * 64, c0 = blockIdx.y * 64, b = blockIdx.z;
  const int lm = t & 63, row = t >> 6;
#pragma unroll
  for (int j = 0; j < 16; ++j) {
    int c = row + j * 4;
    tile[lm][c] = (f16)kf[(size_t)(b * C2 + c0 + c) * Mm + m0 + lm];
  }
  __syncthreads();
#pragma unroll
  for (int j = 0; j < 16; ++j) {
    int m = row + j * 4;
    kfT[(size_t)(b * Mm + m0 + m) * C2 + c0 + lm] = tile[m][lm];
  }
}

// ---------------------------------------------------------------- 3) weights f32 -> f16 in MFMA A-fragment order
__global__ void wrep_kernel(const float* __restrict__ W0, const float* __restrict__ W1,
                            f16* __restrict__ Af0, f16* __restrict__ Af1)
{
  int id = blockIdx.x * 256 + threadIdx.x;
  if (id < CO * K0) {
    int e = id & 7, lane = (id >> 3) & 63, mg = (id >> 9) & 15, ks = id >> 13;
    int m = mg * 16 + (lane & 15), k = ks * 32 + (lane >> 4) * 8 + e;
    Af0[id] = (f16)W0[m * K0 + k];
  }
  if (id < CO * CO) {
    int e = id & 7, lane = (id >> 3) & 63, mg = (id >> 9) & 15, ks = id >> 13;
    int m = mg * 16 + (lane & 15), k = ks * 32 + (lane >> 4) * 8 + e;
    Af1[id] = (f16)W1[m * CO + k];
  }
}

// ---------------------------------------------------------------- 4) fused interp + concat + MLP0 + MLP1 (unchanged from R5)
__global__ __launch_bounds__(256) void mlp_fused(
    const f16* __restrict__ Af0, const f16* __restrict__ Af1,
    const f16* __restrict__ kfT, const float* __restrict__ uf,
    const int* __restrict__ idx, const float* __restrict__ wts,
    const float* __restrict__ bs0, const float* __restrict__ g0,
    const float* __restrict__ be0, const float* __restrict__ rm0, const float* __restrict__ rv0,
    const float* __restrict__ bs1, const float* __restrict__ g1,
    const float* __restrict__ be1, const float* __restrict__ rm1, const float* __restrict__ rv1,
    float* __restrict__ out)
{
  __shared__ __align__(16) char lds[53248];
  const int t = threadIdx.x;
  const int w = t >> 6, l = t & 63, lm = l & 15, qq = l >> 4;
  const int gid = blockIdx.x;
  const int b = gid >> 7, n0 = (gid & 127) * 64;

  float* bn0S = (float*)(lds + 49152);
  float* bn0H = (float*)(lds + 50176);
  float* bn1S = (float*)(lds + 51200);
  float* bn1H = (float*)(lds + 52224);
  {
    float sc0 = g0[t] / sqrtf(rv0[t] + 1e-5f);
    bn0S[t] = sc0; bn0H[t] = (bs0[t] - rm0[t]) * sc0 + be0[t];
    float sc1 = g1[t] / sqrtf(rv1[t] + 1e-5f);
    bn1S[t] = sc1; bn1H[t] = (bs1[t] - rm1[t]) * sc1 + be1[t];
  }

  {
    const int n = t >> 2, kg = t & 3;
    const int base = (b * Nn + n0 + n) * 3;
    int i0 = idx[base], i1 = idx[base + 1], i2 = idx[base + 2];
    float w0 = wts[base], w1 = wts[base + 1], w2 = wts[base + 2];
    f16 w0h = (f16)w0, w1h = (f16)w1, w2h = (f16)w2;
    f16x8 w0v = {w0h, w0h, w0h, w0h, w0h, w0h, w0h, w0h};
    f16x8 w1v = {w1h, w1h, w1h, w1h, w1h, w1h, w1h, w1h};
    f16x8 w2v = {w2h, w2h, w2h, w2h, w2h, w2h, w2h, w2h};
    const f16x8* r0 = (const f16x8*)(kfT + (size_t)(b * Mm + i0) * C2 + kg * 64);
    const f16x8* r1 = (const f16x8*)(kfT + (size_t)(b * Mm + i1) * C2 + kg * 64);
    const f16x8* r2 = (const f16x8*)(kfT + (size_t)(b * Mm + i2) * C2 + kg * 64);
#pragma unroll
    for (int j = 0; j < 8; ++j) {
      f16x8 o = r0[j] * w0v + r1[j] * w1v + r2[j] * w2v;
      int oct = kg * 8 + j;
      *(f16x8*)(lds + n * 768 + ((oct ^ (n & 7)) * 16)) = o;
    }
  }
  {
    const int n = t & 63, cb = (t >> 6) * 32;
    const float* src = uf + (size_t)(b * C1 + cb) * Nn + n0 + n;
#pragma unroll
    for (int jj = 0; jj < 4; ++jj) {
      f16x8 v;
#pragma unroll
      for (int e = 0; e < 8; ++e) v[e] = (f16)src[(size_t)(jj * 8 + e) * Nn];
      int oct = 32 + (cb >> 3) + jj;
      *(f16x8*)(lds + n * 768 + ((oct ^ (n & 7)) * 16)) = v;
    }
  }
  __syncthreads();

  f32x4 acc[4][4] = {};
  {
    f16x8 af[4];
#pragma unroll
    for (int i = 0; i < 4; ++i)
      af[i] = *(const f16x8*)(Af0 + ((size_t)(w * 4 + i) * 64 + l) * 8);
    for (int ks = 0; ks < 12; ++ks) {
      f16x8 afn[4];
      if (ks < 11) {
#pragma unroll
        for (int i = 0; i < 4; ++i)
          afn[i] = *(const f16x8*)(Af0 + ((size_t)((ks + 1) * 16 + w * 4 + i) * 64 + l) * 8);
      }
      f16x8 bf[4];
#pragma unroll
      for (int j = 0; j < 4; ++j) {
        int n = j * 16 + lm;
        bf[j] = *(const f16x8*)(lds + n * 768 + (((ks * 4 + qq) ^ (n & 7)) * 16));
      }
#pragma unroll
      for (int i = 0; i < 4; ++i)
#pragma unroll
        for (int j = 0; j < 4; ++j)
          acc[i][j] = __builtin_amdgcn_mfma_f32_16x16x32_f16(af[i], bf[j], acc[i][j], 0, 0, 0);
#pragma unroll
      for (int i = 0; i < 4; ++i) af[i] = afn[i];
    }
  }
  __syncthreads();

#pragma unroll
  for (int i = 0; i < 4; ++i) {
    const int mq = w * 64 + i * 16 + qq * 4;
    f32x4 s4 = *(const f32x4*)&bn0S[mq];
    f32x4 h4 = *(const f32x4*)&bn0H[mq];
#pragma unroll
    for (int j = 0; j < 4; ++j) {
      int n = j * 16 + lm;
      f16x4 v;
#pragma unroll
      for (int r = 0; r < 4; ++r) v[r] = (f16)fmaxf(fmaf(acc[i][j][r], s4[r], h4[r]), 0.f);
      *(f16x4*)(lds + n * 512 + (((mq >> 3) ^ (n & 7)) * 16) + (mq & 7) * 2) = v;
    }
  }
  __syncthreads();

#pragma unroll
  for (int i = 0; i < 4; ++i)
#pragma unroll
    for (int j = 0; j < 4; ++j) acc[i][j] = f32x4{0.f, 0.f, 0.f, 0.f};
  {
    f16x8 af[4];
#pragma unroll
    for (int i = 0; i < 4; ++i)
      af[i] = *(const f16x8*)(Af1 + ((size_t)(w * 4 + i) * 64 + l) * 8);
    for (int ks = 0; ks < 8; ++ks) {
      f16x8 afn[4];
      if (ks < 7) {
#pragma unroll
        for (int i = 0; i < 4; ++i)
          afn[i] = *(const f16x8*)(Af1 + ((size_t)((ks + 1) * 16 + w * 4 + i) * 64 + l) * 8);
      }
      f16x8 bf[4];
#pragma unroll
      for (int j = 0; j < 4; ++j) {
        int n = j * 16 + lm;
        bf[j] = *(const f16x8*)(lds + n * 512 + (((ks * 4 + qq) ^ (n & 7)) * 16));
      }
#pragma unroll
      for (int i = 0; i < 4; ++i)
#pragma unroll
        for (int j = 0; j < 4; ++j)
          acc[i][j] = __builtin_amdgcn_mfma_f32_16x16x32_f16(af[i], bf[j], acc[i][j], 0, 0, 0);
#pragma unroll
      for (int i = 0; i < 4; ++i) af[i] = afn[i];
    }
  }

#pragma unroll
  for (int i = 0; i < 4; ++i) {
    const int mq = w * 64 + i * 16 + qq * 4;
    f32x4 s4 = *(const f32x4*)&bn1S[mq];
    f32x4 h4 = *(const f32x4*)&bn1H[mq];
#pragma unroll
    for (int r = 0; r < 4; ++r) {
      const int m = mq + r;
#pragma unroll
      for (int j = 0; j < 4; ++j) {
        int n = j * 16 + lm;
        out[(size_t)(b * CO + m) * Nn + n0 + n] = fmaxf(fmaf(acc[i][j][r], s4[r], h4[r]), 0.f);
      }
    }
  }
}

// ---------------------------------------------------------------- launch
extern "C" void kernel_launch(void* const* d_in, const int* in_sizes, int n_in,
                              void* d_out, int out_size, void* d_ws, size_t ws_size,
                              hipStream_t stream)
{
  const float* unknown = (const float*)d_in[0];
  const float* known   = (const float*)d_in[1];
  const float* uf      = (const float*)d_in[2];
  const float* kf      = (const float*)d_in[3];
  const float* W0  = (const float*)d_in[4];
  const float* b0  = (const float*)d_in[5];
  const float* g0  = (const float*)d_in[6];
  const float* be0 = (const float*)d_in[7];
  const float* rm0 = (const float*)d_in[8];
  const float* rv0 = (const float*)d_in[9];
  const float* W1  = (const float*)d_in[10];
  const float* b1  = (const float*)d_in[11];
  const float* g1  = (const float*)d_in[12];
  const float* be1 = (const float*)d_in[13];
  const float* rm1 = (const float*)d_in[14];
  const float* rv1 = (const float*)d_in[15];

  char* ws = (char*)d_ws;
  int*    idx  = (int*)   (ws + 0);          // B*N*3 i32   = 384 KB
  float*  wts  = (float*) (ws + 393216);     // B*N*3 f32   = 384 KB
  f16*    kfT  = (f16*)   (ws + 786432);     // B*M*C2 f16  = 4 MB
  f16*    Af0  = (f16*)   (ws + 4980736);    // 256*384 f16 (fragment-order)
  f16*    Af1  = (f16*)   (ws + 5177344);    // 256*256 f16 (fragment-order)
  float4* dscr = (float4*)(ws + 5308416);    // B*N*4 float4 = 2 MB
  int4*   iscr = (int4*)  (ws + 7405568);    // B*N*4 int4   = 2 MB
  float*  out  = (float*)d_out;              // (B,256,N) f32

  knn_scan  <<<dim3(512), 256, 0, stream>>>(unknown, known, dscr, iscr);
  knn_merge <<<dim3(Bb * Nn / 256), 256, 0, stream>>>(dscr, iscr, idx, wts);
  kft_kernel<<<dim3(Mm / 64, C2 / 64, Bb), 256, 0, stream>>>(kf, kfT);
  wrep_kernel<<<dim3((CO * K0 + 255) / 256), 256, 0, stream>>>(W0, W1, Af0, Af1);
  mlp_fused <<<dim3(Bb * (Nn / 64)), 256, 0, stream>>>(
      Af0, Af1, kfT, uf, idx, wts,
      b0, g0, be0, rm0, rv0, b1, g1, be1, rm1, rv1, out);
}